// Round 8
// baseline (172.745 us; speedup 1.0000x reference)
//
#include <hip/hip_runtime.h>
#include <hip/hip_bf16.h>

// CSSM TinyViT block, fused bf16-MFMA implementation for gfx950.
// B=16,H=32,W=32 -> 16384 rows of C=384. T=8, HID=1536.
// Round 8: 2 independent blocks per CU (BMROWS=32, 256 thr, 73KB LDS) so
// barriers only drain half the CU's waves; transposed gemms (round 7),
// g packed regs, c LDS runs, aco MFMA-only, waves_per_eu(2,2) -> 256-reg
// budget at zero occupancy cost.

#define CCH   384
#define NPIX  16384
#define BMROWS 32
#define NTHR  256          // 4 waves; wave owns 96 chans x 32 pixels
#define LNEPS 1e-6f
#define HBUF  12288        // ushorts per 24KB buffer

typedef __attribute__((ext_vector_type(8))) short bf8_t;   // 8 x bf16
typedef __attribute__((ext_vector_type(4))) float f4_t;    // 4 x f32
typedef __attribute__((ext_vector_type(8))) unsigned short us8_t;

// workspace offsets (ushort units). Each 16x16x32 W-tile = 512 bf16 = 1KB.
// K-MAJOR tile order: tile = kb * (N/16) + n16   (kb = K/32 block)
#define OFF_WU 0u
#define OFF_WG 147456u      // 288 tiles * 512
#define OFF_A  294912u
#define OFF_W1 442368u      // 384x1536 -> 1152 tiles
#define OFF_W2 1032192u     // 1536x384 -> 1152 tiles

__device__ __forceinline__ unsigned short f2bf(float f) {
  return __builtin_bit_cast(unsigned short, __float2bfloat16(f));  // HW RNE cvt
}
__device__ __forceinline__ float bf2f(unsigned short h) {
  union { unsigned u; float f; } x; x.u = ((unsigned)h) << 16;
  return x.f;
}
__device__ __forceinline__ unsigned pack2(float lo, float hi) {
  return (unsigned)f2bf(lo) | ((unsigned)f2bf(hi) << 16);
}
__device__ __forceinline__ float ulo(unsigned u) {
  union { unsigned x; float f; } v; v.x = u << 16; return v.f;
}
__device__ __forceinline__ float uhi(unsigned u) {
  union { unsigned x; float f; } v; v.x = u & 0xffff0000u; return v.f;
}
__device__ __forceinline__ float fsigmoid(float z) {
  return __builtin_amdgcn_rcpf(1.f + __expf(-z));
}

// Pack all five f32 weights into bf16 fragment order, k-major tiles:
// P[off + tile*512 + lane*8 + j] = W[kb*32 + (lane>>4)*8 + j][n16*16 + (lane&15)]
// Used as the MFMA A-operand: A[row=n][k] = W[k][n] (i.e. W^T).
__global__ void pack_all(const float* __restrict__ Wu, const float* __restrict__ Wg,
                         const float* __restrict__ A,  const float* __restrict__ W1,
                         const float* __restrict__ W2, unsigned short* __restrict__ P) {
  const int gid = blockIdx.x * blockDim.x + threadIdx.x;
  const int l = gid & 63;
  int tile = gid >> 6;
  const float* W; int N; unsigned off; int t;
  if      (tile <  288) { W = Wu; N = 384;  off = OFF_WU; t = tile;        }
  else if (tile <  576) { W = Wg; N = 384;  off = OFF_WG; t = tile - 288;  }
  else if (tile <  864) { W = A;  N = 384;  off = OFF_A;  t = tile - 576;  }
  else if (tile < 2016) { W = W1; N = 1536; off = OFF_W1; t = tile - 864;  }
  else if (tile < 3168) { W = W2; N = 384;  off = OFF_W2; t = tile - 2016; }
  else return;
  const int ntn = N >> 4;
  const int kb  = t / ntn, n16 = t % ntn;
  const int krow = kb * 32 + ((l >> 4) << 3);
  const int col  = n16 * 16 + (l & 15);
  us8_t pk;
  #pragma unroll
  for (int j = 0; j < 8; ++j) pk[j] = f2bf(W[(size_t)(krow + j) * N + col]);
  *reinterpret_cast<us8_t*>(P + off + ((size_t)t << 9) + (l << 3)) = pk;
}

// acc[2][6] += W^T(6 chan-tiles, packed k-major) * X^T(LDS, 2 pixel-tiles).
// acc[pt][ct]: D[chan][pix] 16x16 tiles; lane holds 4 consecutive chans of
// pixel (lane&15).
template <int NKB>
__device__ __forceinline__ void gemm_acc(const unsigned short* sb,
                                         const unsigned short* __restrict__ wt,
                                         int kb0, int ntn, int n16base,
                                         int lane, f4_t acc[2][6]) {
  const int r    = lane & 15;
  const int sw   = (lane & 7) << 3;
  const int koff = (lane >> 4) << 3;
  #pragma unroll 4
  for (int kb = 0; kb < NKB; ++kb) {
    const int ac = (kb * 32 + koff) ^ sw;
    bf8_t p[2];                       // B-operand: pixel tiles from LDS
    p[0] = *reinterpret_cast<const bf8_t*>(&sb[r * CCH + ac]);
    p[1] = *reinterpret_cast<const bf8_t*>(&sb[(16 + r) * CCH + ac]);
    const unsigned short* bt =
        wt + (((size_t)((kb0 + kb) * ntn + n16base) << 9) + (lane << 3));
    #pragma unroll
    for (int ct = 0; ct < 6; ++ct) {
      const bf8_t w = *reinterpret_cast<const bf8_t*>(bt + (ct << 9));
      acc[0][ct] = __builtin_amdgcn_mfma_f32_16x16x32_bf16(w, p[0], acc[0][ct], 0, 0, 0);
      acc[1][ct] = __builtin_amdgcn_mfma_f32_16x16x32_bf16(w, p[1], acc[1][ct], 0, 0, 0);
    }
  }
}

// write transposed C/D tile into swizzled bf16 LDS [pix][chan] buffer:
// each (pt,ct) quad = 4 consecutive chans of one pixel -> one ds_write_b64.
__device__ __forceinline__ void write_tile(unsigned short* sb, const f4_t t[2][6],
                                           int nw, int lane) {
  const int pixb = lane & 15;
  const int ch0  = nw * 96 + ((lane >> 4) << 2);
  #pragma unroll
  for (int pt = 0; pt < 2; ++pt) {
    const int pix = pt * 16 + pixb;
    const int swz = (pix & 7) << 3;
    #pragma unroll
    for (int ct = 0; ct < 6; ++ct) {
      uint2 v;
      v.x = pack2(t[pt][ct][0], t[pt][ct][1]);
      v.y = pack2(t[pt][ct][2], t[pt][ct][3]);
      *reinterpret_cast<uint2*>(&sb[pix * CCH + ((ch0 + ct * 16) ^ swz)]) = v;
    }
  }
}

// c runs: wave-linear conflict-free layout [6 blocks][256 tid][8 bf16]
__device__ __forceinline__ void store_crun(unsigned short* buf, const f4_t t[2][6],
                                           int tid) {
  #pragma unroll
  for (int b = 0; b < 6; ++b) {
    us8_t pk;
    #pragma unroll
    for (int m = 0; m < 8; ++m) {
      const int k = b * 8 + m;
      pk[m] = f2bf(t[k / 24][(k % 24) >> 2][k & 3]);
    }
    *reinterpret_cast<us8_t*>(&buf[b * 2048 + tid * 8]) = pk;
  }
}

// acc = g*acc + c, g from packed-bf16 regs, c streamed from LDS runs
__device__ __forceinline__ void fma_gc(f4_t acc[2][6], const unsigned gp[2][6][2],
                                       const unsigned short* cb, int tid) {
  #pragma unroll
  for (int b = 0; b < 6; ++b) {
    const us8_t cv = *reinterpret_cast<const us8_t*>(&cb[b * 2048 + tid * 8]);
    #pragma unroll
    for (int m = 0; m < 8; ++m) {
      const int k = b * 8 + m, pt = k / 24, ct = (k % 24) >> 2, j = k & 3;
      const unsigned g = gp[pt][ct][j >> 1];
      const float gf = (j & 1) ? uhi(g) : ulo(g);
      acc[pt][ct][j] = gf * acc[pt][ct][j] + bf2f(cv[m]);
    }
  }
}

__device__ __forceinline__ void zero_acc(f4_t a[2][6]) {
  #pragma unroll
  for (int pt = 0; pt < 2; ++pt)
    #pragma unroll
    for (int ct = 0; ct < 6; ++ct) a[pt][ct] = (f4_t){0.f, 0.f, 0.f, 0.f};
}

__global__ __launch_bounds__(NTHR)
__attribute__((amdgpu_waves_per_eu(2, 2)))
void cssm_main(
    const float* __restrict__ x,
    const float* __restrict__ n1s, const float* __restrict__ n1b,
    const float* __restrict__ bu, const float* __restrict__ bg,
    const float* __restrict__ n2s, const float* __restrict__ n2b,
    const float* __restrict__ b1, const float* __restrict__ b2,
    const unsigned short* __restrict__ wp,
    float* __restrict__ out) {
  __shared__ unsigned short sm[3 * HBUF];   // bA | bB | bC  (24KB each)
  __shared__ float part[BMROWS][4][2];      // per-(pixel,wave) LN2 partials
  __shared__ float srow[BMROWS][2];         // LN2 mu, rs per pixel
  unsigned short* bA = sm;                  // xn -> h ping -> xn2
  unsigned short* bB = sm + HBUF;           // h pong -> m tiles
  unsigned short* bC = sm + 2 * HBUF;       // c runs -> h8 tile

  const int tid = threadIdx.x;
  const int lane = tid & 63;
  const int nw = tid >> 6;                  // wave chan-slot: chans nw*96..+95
  const int r0 = blockIdx.x * BMROWS;
  const int pixb = lane & 15;
  const int ch0  = nw * 96 + ((lane >> 4) << 2);

  // ---------------- Phase A: LN1(x) -> bA (bf16 [pix][chan], swizzled) -----
  {
    const int row = tid >> 3, seg = tid & 7;
    const float* xr = x + (size_t)(r0 + row) * CCH + seg * 48;
    float v[48];
    float s = 0.f, s2 = 0.f;
    #pragma unroll
    for (int i = 0; i < 12; ++i) {
      const f4_t t = reinterpret_cast<const f4_t*>(xr)[i];
      #pragma unroll
      for (int j = 0; j < 4; ++j) { const float f = t[j]; v[i * 4 + j] = f; s += f; s2 += f * f; }
    }
    #pragma unroll
    for (int o = 1; o < 8; o <<= 1) { s += __shfl_xor(s, o, 64); s2 += __shfl_xor(s2, o, 64); }
    const float mu = s * (1.f / CCH);
    const float rs = rsqrtf(fmaxf(s2 * (1.f / CCH) - mu * mu, 0.f) + LNEPS);
    const int sw = (row & 7) << 3;
    #pragma unroll
    for (int g8 = 0; g8 < 6; ++g8) {
      us8_t pk;
      #pragma unroll
      for (int j = 0; j < 8; ++j) {
        const int colc = seg * 48 + g8 * 8 + j;
        pk[j] = f2bf((v[g8 * 8 + j] - mu) * rs * n1s[colc] + n1b[colc]);
      }
      *reinterpret_cast<us8_t*>(&bA[row * CCH + ((seg * 48 + g8 * 8) ^ sw)]) = pk;
    }
  }
  __syncthreads();

  // ---------------- Phase A2: g -> packed regs; c -> bC runs; h1 -> bB -----
  f4_t acc[2][6];
  unsigned gp[2][6][2];
  zero_acc(acc);
  gemm_acc<12>(bA, wp + OFF_WG, 0, 24, nw * 6, lane, acc);
  #pragma unroll
  for (int ct = 0; ct < 6; ++ct) {
    const f4_t bgq = *reinterpret_cast<const f4_t*>(&bg[ch0 + ct * 16]);
    #pragma unroll
    for (int pt = 0; pt < 2; ++pt) {
      gp[pt][ct][0] = pack2(fsigmoid(acc[pt][ct][0] + bgq[0]),
                            fsigmoid(acc[pt][ct][1] + bgq[1]));
      gp[pt][ct][1] = pack2(fsigmoid(acc[pt][ct][2] + bgq[2]),
                            fsigmoid(acc[pt][ct][3] + bgq[3]));
    }
  }
  zero_acc(acc);
  gemm_acc<12>(bA, wp + OFF_WU, 0, 24, nw * 6, lane, acc);
  #pragma unroll
  for (int ct = 0; ct < 6; ++ct) {
    const f4_t buq = *reinterpret_cast<const f4_t*>(&bu[ch0 + ct * 16]);
    #pragma unroll
    for (int pt = 0; pt < 2; ++pt)
      #pragma unroll
      for (int j = 0; j < 4; ++j) {
        const unsigned g = gp[pt][ct][j >> 1];
        const float gf = (j & 1) ? uhi(g) : ulo(g);
        acc[pt][ct][j] = (1.f - gf) * (acc[pt][ct][j] + buq[j]);
      }
  }
  store_crun(bC, acc, tid);                 // c (bf16 runs, own slots)
  write_tile(bB, acc, nw, lane);            // h1 = c
  __syncthreads();

  // ---------------- Phase B: h' = g*(h@A) + c, ping-pong bB/bA -------------
  {
    unsigned short* cur = bB;
    unsigned short* alt = bA;
    #pragma unroll 1
    for (int stp = 0; stp < 7; ++stp) {     // h2..h8
      zero_acc(acc);
      gemm_acc<12>(cur, wp + OFF_A, 0, 24, nw * 6, lane, acc);
      fma_gc(acc, gp, bC, tid);
      if (stp < 6) {
        write_tile(alt, acc, nw, lane);     // write buffer nobody is reading
        unsigned short* t = cur; cur = alt; alt = t;
        __syncthreads();
      }
    }
  }
  __syncthreads();                          // all fma_gc reads of bC done

  // ------- Phase C: h8 -> bC tile; y = x + h8; LN2 -> xn2 in bA ------------
  write_tile(bC, acc, nw, lane);            // h8 (own quads, reread in E)
  #pragma unroll
  for (int pt = 0; pt < 2; ++pt) {
    const int pix = pt * 16 + pixb;
    float s = 0.f, s2 = 0.f;
    #pragma unroll
    for (int ct = 0; ct < 6; ++ct) {
      const f4_t xq = *reinterpret_cast<const f4_t*>(
          &x[(size_t)(r0 + pix) * CCH + ch0 + ct * 16]);
      #pragma unroll
      for (int j = 0; j < 4; ++j) {
        const float y = xq[j] + acc[pt][ct][j];
        acc[pt][ct][j] = y;
        s += y; s2 += y * y;
      }
    }
    s += __shfl_xor(s, 16, 64); s2 += __shfl_xor(s2, 16, 64);
    s += __shfl_xor(s, 32, 64); s2 += __shfl_xor(s2, 32, 64);
    if (lane < 16) { part[pix][nw][0] = s; part[pix][nw][1] = s2; }
  }
  __syncthreads();
  if (tid < BMROWS) {
    float s = 0.f, s2 = 0.f;
    #pragma unroll
    for (int w = 0; w < 4; ++w) { s += part[tid][w][0]; s2 += part[tid][w][1]; }
    const float mu = s * (1.f / CCH);
    srow[tid][0] = mu;
    srow[tid][1] = rsqrtf(fmaxf(s2 * (1.f / CCH) - mu * mu, 0.f) + LNEPS);
  }
  __syncthreads();
  {
    f4_t scq[6], bsq[6];
    #pragma unroll
    for (int ct = 0; ct < 6; ++ct) {
      scq[ct] = *reinterpret_cast<const f4_t*>(&n2s[ch0 + ct * 16]);
      bsq[ct] = *reinterpret_cast<const f4_t*>(&n2b[ch0 + ct * 16]);
    }
    #pragma unroll
    for (int pt = 0; pt < 2; ++pt) {
      const int pix = pt * 16 + pixb;
      const float mu = srow[pix][0], rs = srow[pix][1];
      #pragma unroll
      for (int ct = 0; ct < 6; ++ct)
        #pragma unroll
        for (int j = 0; j < 4; ++j)
          acc[pt][ct][j] = (acc[pt][ct][j] - mu) * rs * scq[ct][j] + bsq[ct][j];
    }
    write_tile(bA, acc, nw, lane);          // xn2 (bA dead: held h6)
  }
  __syncthreads();

  // ---------------- Phase D: MLP in 4 HID-chunks of 384 --------------------
  f4_t aco[2][6];
  zero_acc(aco);                            // MFMA-only until E -> AGPR
  #pragma unroll 1
  for (int ch = 0; ch < 4; ++ch) {
    zero_acc(acc);
    gemm_acc<12>(bA, wp + OFF_W1, 0, 96, ch * 24 + nw * 6, lane, acc);
    #pragma unroll
    for (int ct = 0; ct < 6; ++ct) {
      const f4_t b1q = *reinterpret_cast<const f4_t*>(&b1[ch * 384 + ch0 + ct * 16]);
      #pragma unroll
      for (int pt = 0; pt < 2; ++pt)
        #pragma unroll
        for (int j = 0; j < 4; ++j) {
          // gelu(z) = z * sigmoid(1.595769122*(z + 0.044715 z^3))  (tanh form)
          const float z = acc[pt][ct][j] + b1q[j];
          const float w = 1.5957691216057308f * (z + 0.044715f * z * z * z);
          acc[pt][ct][j] = z * fsigmoid(w);
        }
    }
    write_tile(bB, acc, nw, lane);
    __syncthreads();
    gemm_acc<12>(bB, wp + OFF_W2, ch * 12, 24, nw * 6, lane, aco);
    if (ch < 3) __syncthreads();            // before next chunk overwrites bB
  }

  // ---------------- Phase E: out = x + h8 + mlp + b2 (vector) --------------
  {
    f4_t b2q[6];
    #pragma unroll
    for (int ct = 0; ct < 6; ++ct)
      b2q[ct] = *reinterpret_cast<const f4_t*>(&b2[ch0 + ct * 16]);
    #pragma unroll
    for (int pt = 0; pt < 2; ++pt) {
      const int pix = pt * 16 + pixb;
      const int swz = (pix & 7) << 3;
      #pragma unroll
      for (int ct = 0; ct < 6; ++ct) {
        const size_t pos = (size_t)(r0 + pix) * CCH + ch0 + ct * 16;
        const f4_t xq = *reinterpret_cast<const f4_t*>(&x[pos]);
        const uint2 hv = *reinterpret_cast<const uint2*>(
            &bC[pix * CCH + ((ch0 + ct * 16) ^ swz)]);
        f4_t o;
        o[0] = xq[0] + ulo(hv.x) + aco[pt][ct][0] + b2q[ct][0];
        o[1] = xq[1] + uhi(hv.x) + aco[pt][ct][1] + b2q[ct][1];
        o[2] = xq[2] + ulo(hv.y) + aco[pt][ct][2] + b2q[ct][2];
        o[3] = xq[3] + uhi(hv.y) + aco[pt][ct][3] + b2q[ct][3];
        *reinterpret_cast<f4_t*>(&out[pos]) = o;
      }
    }
  }
}

extern "C" void kernel_launch(void* const* d_in, const int* in_sizes, int n_in,
                              void* d_out, int out_size, void* d_ws, size_t ws_size,
                              hipStream_t stream) {
  const float* x   = (const float*)d_in[0];
  const float* n1s = (const float*)d_in[1];
  const float* n1b = (const float*)d_in[2];
  const float* Wu  = (const float*)d_in[3];
  const float* bu  = (const float*)d_in[4];
  const float* Wg  = (const float*)d_in[5];
  const float* bg  = (const float*)d_in[6];
  const float* A   = (const float*)d_in[7];
  const float* n2s = (const float*)d_in[8];
  const float* n2b = (const float*)d_in[9];
  const float* W1  = (const float*)d_in[10];
  const float* b1  = (const float*)d_in[11];
  const float* W2  = (const float*)d_in[12];
  const float* b2  = (const float*)d_in[13];
  unsigned short* wp = (unsigned short*)d_ws;
  float* out = (float*)d_out;

  // pack all weights to bf16 fragment order (one launch; 3168 tiles * 64 lanes)
  pack_all<<<(3168 * 64) / 256, 256, 0, stream>>>(Wu, Wg, A, W1, W2, wp);

  cssm_main<<<NPIX / BMROWS, NTHR, 0, stream>>>(
      x, n1s, n1b, bu, bg, n2s, n2b, b1, b2, wp, out);
}

// Round 9
// 131.354 us; speedup vs baseline: 1.3151x; 1.3151x over previous
//
#include <hip/hip_runtime.h>
#include <hip/hip_bf16.h>

// CSSM TinyViT block, fused bf16-MFMA implementation for gfx950.
// B=16,H=32,W=32 -> 16384 rows of C=384. T=8, HID=1536.
// Round 9 = round 7 base (best, 135us) +
//  (1) c in packed-bf16 registers (no LDS c-runs -> shorter recurrence
//      critical path, bC now holds only h8, zero barriers for it),
//  (2) padded LDS stride 392 (conflict-minimal, no XOR addressing VALU),
//  (3) exp2-folded sigmoid/gelu,
//  (4) barrier diet: 1/step recurrence (ping-pong), no post-loop barrier.

#define CCH   384          // global row stride (elements)
#define SB    392          // LDS row stride (ushorts): 384 + 8 pad
#define NPIX  16384
#define BMROWS 64
#define NTHR  512          // 8 waves; wave owns 48 chans x 64 pixels
#define LNEPS 1e-6f
#define HBUF  (BMROWS * SB)   // 25088 ushorts = 49KB per buffer

typedef __attribute__((ext_vector_type(8))) short bf8_t;   // 8 x bf16
typedef __attribute__((ext_vector_type(4))) float f4_t;    // 4 x f32
typedef __attribute__((ext_vector_type(8))) unsigned short us8_t;

// workspace offsets (ushort units). Each 16x16x32 W-tile = 512 bf16 = 1KB.
// K-MAJOR tile order: tile = kb * (N/16) + n16   (kb = K/32 block)
#define OFF_WU 0u
#define OFF_WG 147456u      // 288 tiles * 512
#define OFF_A  294912u
#define OFF_W1 442368u      // 384x1536 -> 1152 tiles
#define OFF_W2 1032192u     // 1536x384 -> 1152 tiles

__device__ __forceinline__ unsigned short f2bf(float f) {
  return __builtin_bit_cast(unsigned short, __float2bfloat16(f));  // HW RNE cvt
}
__device__ __forceinline__ unsigned pack2(float lo, float hi) {
  return (unsigned)f2bf(lo) | ((unsigned)f2bf(hi) << 16);
}
__device__ __forceinline__ float ulo(unsigned u) {
  union { unsigned x; float f; } v; v.x = u << 16; return v.f;
}
__device__ __forceinline__ float uhi(unsigned u) {
  union { unsigned x; float f; } v; v.x = u & 0xffff0000u; return v.f;
}
// sigmoid(z) = 1/(1+2^(-z*log2e))
__device__ __forceinline__ float fsigmoid(float z) {
  return __builtin_amdgcn_rcpf(1.f + exp2f(z * -1.44269504088896f));
}

// Pack all five f32 weights into bf16 fragment order, k-major tiles:
// P[off + tile*512 + lane*8 + j] = W[kb*32 + (lane>>4)*8 + j][n16*16 + (lane&15)]
// Used as the MFMA A-operand: A[row=n][k] = W[k][n] (i.e. W^T).
__global__ void pack_all(const float* __restrict__ Wu, const float* __restrict__ Wg,
                         const float* __restrict__ A,  const float* __restrict__ W1,
                         const float* __restrict__ W2, unsigned short* __restrict__ P) {
  const int gid = blockIdx.x * blockDim.x + threadIdx.x;
  const int l = gid & 63;
  int tile = gid >> 6;
  const float* W; int N; unsigned off; int t;
  if      (tile <  288) { W = Wu; N = 384;  off = OFF_WU; t = tile;        }
  else if (tile <  576) { W = Wg; N = 384;  off = OFF_WG; t = tile - 288;  }
  else if (tile <  864) { W = A;  N = 384;  off = OFF_A;  t = tile - 576;  }
  else if (tile < 2016) { W = W1; N = 1536; off = OFF_W1; t = tile - 864;  }
  else if (tile < 3168) { W = W2; N = 384;  off = OFF_W2; t = tile - 2016; }
  else return;
  const int ntn = N >> 4;
  const int kb  = t / ntn, n16 = t % ntn;
  const int krow = kb * 32 + ((l >> 4) << 3);
  const int col  = n16 * 16 + (l & 15);
  us8_t pk;
  #pragma unroll
  for (int j = 0; j < 8; ++j) pk[j] = f2bf(W[(size_t)(krow + j) * N + col]);
  *reinterpret_cast<us8_t*>(P + off + ((size_t)t << 9) + (l << 3)) = pk;
}

// acc[4][3] += W^T(3 chan-tiles, packed k-major) * X^T(LDS, 4 pixel-tiles).
// acc[pt][ct]: D[chan][pix] 16x16 tiles; lane holds 4 consecutive chans of
// pixel (lane&15). LDS padded stride SB -> conflict-minimal, no XOR.
template <int NKB>
__device__ __forceinline__ void gemm_acc(const unsigned short* sb,
                                         const unsigned short* __restrict__ wt,
                                         int kb0, int ntn, int n16base,
                                         int lane, f4_t acc[4][3]) {
  const int r    = lane & 15;
  const int koff = (lane >> 4) << 3;
  #pragma unroll 4
  for (int kb = 0; kb < NKB; ++kb) {
    const int ac = kb * 32 + koff;
    bf8_t p[4];                       // B-operand: pixel tiles from LDS
    #pragma unroll
    for (int pt = 0; pt < 4; ++pt)
      p[pt] = *reinterpret_cast<const bf8_t*>(&sb[(pt * 16 + r) * SB + ac]);
    const unsigned short* bt =
        wt + (((size_t)((kb0 + kb) * ntn + n16base) << 9) + (lane << 3));
    #pragma unroll
    for (int ct = 0; ct < 3; ++ct) {
      const bf8_t w = *reinterpret_cast<const bf8_t*>(bt + (ct << 9));
      #pragma unroll
      for (int pt = 0; pt < 4; ++pt)
        acc[pt][ct] = __builtin_amdgcn_mfma_f32_16x16x32_bf16(w, p[pt], acc[pt][ct], 0, 0, 0);
    }
  }
}

// write transposed C/D tile into padded bf16 LDS [pix][chan] buffer:
// each (pt,ct) quad = 4 consecutive chans of one pixel -> one ds_write_b64.
__device__ __forceinline__ void write_tile(unsigned short* sb, const f4_t t[4][3],
                                           int nw, int lane) {
  const int pixb = lane & 15;
  const int ch0  = nw * 48 + ((lane >> 4) << 2);
  #pragma unroll
  for (int pt = 0; pt < 4; ++pt) {
    const int pix = pt * 16 + pixb;
    #pragma unroll
    for (int ct = 0; ct < 3; ++ct) {
      uint2 v;
      v.x = pack2(t[pt][ct][0], t[pt][ct][1]);
      v.y = pack2(t[pt][ct][2], t[pt][ct][3]);
      *reinterpret_cast<uint2*>(&sb[pix * SB + ch0 + ct * 16]) = v;
    }
  }
}

__device__ __forceinline__ void zero_acc(f4_t a[4][3]) {
  #pragma unroll
  for (int pt = 0; pt < 4; ++pt)
    #pragma unroll
    for (int ct = 0; ct < 3; ++ct) a[pt][ct] = (f4_t){0.f, 0.f, 0.f, 0.f};
}

__global__ __launch_bounds__(NTHR, 1) void cssm_main(
    const float* __restrict__ x,
    const float* __restrict__ n1s, const float* __restrict__ n1b,
    const float* __restrict__ bu, const float* __restrict__ bg,
    const float* __restrict__ n2s, const float* __restrict__ n2b,
    const float* __restrict__ b1, const float* __restrict__ b2,
    const unsigned short* __restrict__ wp,
    float* __restrict__ out) {
  __shared__ unsigned short sm[3 * HBUF];   // bA | bB | bC
  __shared__ float part[64][8][2];          // per-(pixel,wave) LN2 partials
  __shared__ float srow[64][2];             // LN2 mu, rs per pixel
  unsigned short* bA = sm;                  // xn -> h ping -> xn2
  unsigned short* bB = sm + HBUF;           // h pong -> m tiles
  unsigned short* bC = sm + 2 * HBUF;       // h8 (same-thread write/read only)

  const int tid = threadIdx.x;
  const int lane = tid & 63;
  const int nw = tid >> 6;                  // wave chan-slot: chans nw*48..+47
  const int r0 = blockIdx.x * BMROWS;
  const int pixb = lane & 15;
  const int ch0  = nw * 48 + ((lane >> 4) << 2);

  // ---------------- Phase A: LN1(x) -> bA (bf16 [pix][chan], padded) -------
  {
    const int row = tid >> 3, seg = tid & 7;
    const float* xr = x + (size_t)(r0 + row) * CCH + seg * 48;
    float v[48];
    float s = 0.f, s2 = 0.f;
    #pragma unroll
    for (int i = 0; i < 12; ++i) {
      const f4_t t = reinterpret_cast<const f4_t*>(xr)[i];
      #pragma unroll
      for (int j = 0; j < 4; ++j) { const float f = t[j]; v[i * 4 + j] = f; s += f; s2 += f * f; }
    }
    #pragma unroll
    for (int o = 1; o < 8; o <<= 1) { s += __shfl_xor(s, o, 64); s2 += __shfl_xor(s2, o, 64); }
    const float mu = s * (1.f / CCH);
    const float rs = rsqrtf(fmaxf(s2 * (1.f / CCH) - mu * mu, 0.f) + LNEPS);
    #pragma unroll
    for (int g8 = 0; g8 < 6; ++g8) {
      us8_t pk;
      #pragma unroll
      for (int j = 0; j < 8; ++j) {
        const int colc = seg * 48 + g8 * 8 + j;
        pk[j] = f2bf((v[g8 * 8 + j] - mu) * rs * n1s[colc] + n1b[colc]);
      }
      *reinterpret_cast<us8_t*>(&bA[row * SB + seg * 48 + g8 * 8]) = pk;
    }
  }
  __syncthreads();

  // ---------------- Phase A2: g, c -> packed regs; h1 -> bB ----------------
  f4_t acc[4][3];
  unsigned gp[4][3][2], cp[4][3][2];
  zero_acc(acc);
  gemm_acc<12>(bA, wp + OFF_WG, 0, 24, nw * 3, lane, acc);
  #pragma unroll
  for (int ct = 0; ct < 3; ++ct) {
    const f4_t bgq = *reinterpret_cast<const f4_t*>(&bg[ch0 + ct * 16]);
    #pragma unroll
    for (int pt = 0; pt < 4; ++pt) {
      gp[pt][ct][0] = pack2(fsigmoid(acc[pt][ct][0] + bgq[0]),
                            fsigmoid(acc[pt][ct][1] + bgq[1]));
      gp[pt][ct][1] = pack2(fsigmoid(acc[pt][ct][2] + bgq[2]),
                            fsigmoid(acc[pt][ct][3] + bgq[3]));
    }
  }
  zero_acc(acc);
  gemm_acc<12>(bA, wp + OFF_WU, 0, 24, nw * 3, lane, acc);
  #pragma unroll
  for (int ct = 0; ct < 3; ++ct) {
    const f4_t buq = *reinterpret_cast<const f4_t*>(&bu[ch0 + ct * 16]);
    #pragma unroll
    for (int pt = 0; pt < 4; ++pt) {
      #pragma unroll
      for (int p = 0; p < 2; ++p) {
        const unsigned g = gp[pt][ct][p];
        const float c0 = (1.f - ulo(g)) * (acc[pt][ct][2 * p]     + buq[2 * p]);
        const float c1 = (1.f - uhi(g)) * (acc[pt][ct][2 * p + 1] + buq[2 * p + 1]);
        acc[pt][ct][2 * p] = c0; acc[pt][ct][2 * p + 1] = c1;
        cp[pt][ct][p] = pack2(c0, c1);
      }
    }
  }
  write_tile(bB, acc, nw, lane);            // h1 = c (bA reads done above)
  __syncthreads();

  // ---------------- Phase B: h' = g*(h@A) + c, ping-pong bB/bA -------------
  {
    unsigned short* cur = bB;
    unsigned short* alt = bA;
    #pragma unroll 1
    for (int stp = 0; stp < 7; ++stp) {     // h2..h8
      zero_acc(acc);
      gemm_acc<12>(cur, wp + OFF_A, 0, 24, nw * 3, lane, acc);
      #pragma unroll
      for (int pt = 0; pt < 4; ++pt)
        #pragma unroll
        for (int ct = 0; ct < 3; ++ct)
          #pragma unroll
          for (int p = 0; p < 2; ++p) {
            const unsigned g = gp[pt][ct][p], c = cp[pt][ct][p];
            acc[pt][ct][2 * p]     = ulo(g) * acc[pt][ct][2 * p]     + ulo(c);
            acc[pt][ct][2 * p + 1] = uhi(g) * acc[pt][ct][2 * p + 1] + uhi(c);
          }
      if (stp < 6) {
        write_tile(alt, acc, nw, lane);     // write buffer nobody is reading
        unsigned short* t = cur; cur = alt; alt = t;
        __syncthreads();
      }
    }
  }
  // h7 was in bB (read by all), h6 in bA (reads fenced by stp5 barrier).

  // ------- Phase C: h8 -> bC (own quads); y = x + h8; LN2 -> xn2 in bA -----
  write_tile(bC, acc, nw, lane);            // same-thread reread in E
  #pragma unroll
  for (int pt = 0; pt < 4; ++pt) {
    const int pix = pt * 16 + pixb;
    float s = 0.f, s2 = 0.f;
    #pragma unroll
    for (int ct = 0; ct < 3; ++ct) {
      const f4_t xq = *reinterpret_cast<const f4_t*>(
          &x[(size_t)(r0 + pix) * CCH + ch0 + ct * 16]);
      #pragma unroll
      for (int j = 0; j < 4; ++j) {
        const float y = xq[j] + acc[pt][ct][j];
        acc[pt][ct][j] = y;
        s += y; s2 += y * y;
      }
    }
    s += __shfl_xor(s, 16, 64); s2 += __shfl_xor(s2, 16, 64);
    s += __shfl_xor(s, 32, 64); s2 += __shfl_xor(s2, 32, 64);
    if (lane < 16) { part[pix][nw][0] = s; part[pix][nw][1] = s2; }
  }
  __syncthreads();
  if (tid < 64) {
    float s = 0.f, s2 = 0.f;
    #pragma unroll
    for (int w = 0; w < 8; ++w) { s += part[tid][w][0]; s2 += part[tid][w][1]; }
    const float mu = s * (1.f / CCH);
    srow[tid][0] = mu;
    srow[tid][1] = rsqrtf(fmaxf(s2 * (1.f / CCH) - mu * mu, 0.f) + LNEPS);
  }
  __syncthreads();
  {
    f4_t scq[3], bsq[3];
    #pragma unroll
    for (int ct = 0; ct < 3; ++ct) {
      scq[ct] = *reinterpret_cast<const f4_t*>(&n2s[ch0 + ct * 16]);
      bsq[ct] = *reinterpret_cast<const f4_t*>(&n2b[ch0 + ct * 16]);
    }
    #pragma unroll
    for (int pt = 0; pt < 4; ++pt) {
      const int pix = pt * 16 + pixb;
      const float mu = srow[pix][0], rs = srow[pix][1];
      #pragma unroll
      for (int ct = 0; ct < 3; ++ct)
        #pragma unroll
        for (int j = 0; j < 4; ++j)
          acc[pt][ct][j] = (acc[pt][ct][j] - mu) * rs * scq[ct][j] + bsq[ct][j];
    }
    write_tile(bA, acc, nw, lane);          // xn2 (bA reads fenced at stp5)
  }
  __syncthreads();

  // ---------------- Phase D: MLP in 4 HID-chunks of 384 --------------------
  f4_t aco[4][3];
  zero_acc(aco);                            // MFMA-only until E -> AGPR
  #pragma unroll 1
  for (int ch = 0; ch < 4; ++ch) {
    zero_acc(acc);
    gemm_acc<12>(bA, wp + OFF_W1, 0, 96, ch * 24 + nw * 3, lane, acc);
    #pragma unroll
    for (int ct = 0; ct < 3; ++ct) {
      const f4_t b1q = *reinterpret_cast<const f4_t*>(&b1[ch * 384 + ch0 + ct * 16]);
      #pragma unroll
      for (int pt = 0; pt < 4; ++pt)
        #pragma unroll
        for (int j = 0; j < 4; ++j) {
          // gelu(z) = z * sigmoid(1.595769122*(z + 0.044715 z^3))
          //         = z / (1 + 2^(-2.3021178*(z + 0.044715 z^3)))
          const float z = acc[pt][ct][j] + b1q[j];
          const float m = z * z;
          const float t = z * fmaf(m, 0.044715f, 1.0f);
          const float e = exp2f(t * -2.30211774f);
          acc[pt][ct][j] = z * __builtin_amdgcn_rcpf(1.f + e);
        }
    }
    write_tile(bB, acc, nw, lane);
    __syncthreads();
    gemm_acc<12>(bB, wp + OFF_W2, ch * 12, 24, nw * 3, lane, aco);
    if (ch < 3) __syncthreads();            // before next chunk overwrites bB
  }

  // ---------------- Phase E: out = x + h8 + mlp + b2 (vector) --------------
  {
    f4_t b2q[3];
    #pragma unroll
    for (int ct = 0; ct < 3; ++ct)
      b2q[ct] = *reinterpret_cast<const f4_t*>(&b2[ch0 + ct * 16]);
    #pragma unroll
    for (int pt = 0; pt < 4; ++pt) {
      const int pix = pt * 16 + pixb;
      #pragma unroll
      for (int ct = 0; ct < 3; ++ct) {
        const size_t pos = (size_t)(r0 + pix) * CCH + ch0 + ct * 16;
        const f4_t xq = *reinterpret_cast<const f4_t*>(&x[pos]);
        const uint2 hv = *reinterpret_cast<const uint2*>(
            &bC[pix * SB + ch0 + ct * 16]);
        f4_t o;
        o[0] = xq[0] + ulo(hv.x) + aco[pt][ct][0] + b2q[ct][0];
        o[1] = xq[1] + uhi(hv.x) + aco[pt][ct][1] + b2q[ct][1];
        o[2] = xq[2] + ulo(hv.y) + aco[pt][ct][2] + b2q[ct][2];
        o[3] = xq[3] + uhi(hv.y) + aco[pt][ct][3] + b2q[ct][3];
        *reinterpret_cast<f4_t*>(&out[pos]) = o;
      }
    }
  }
}

extern "C" void kernel_launch(void* const* d_in, const int* in_sizes, int n_in,
                              void* d_out, int out_size, void* d_ws, size_t ws_size,
                              hipStream_t stream) {
  const float* x   = (const float*)d_in[0];
  const float* n1s = (const float*)d_in[1];
  const float* n1b = (const float*)d_in[2];
  const float* Wu  = (const float*)d_in[3];
  const float* bu  = (const float*)d_in[4];
  const float* Wg  = (const float*)d_in[5];
  const float* bg  = (const float*)d_in[6];
  const float* A   = (const float*)d_in[7];
  const float* n2s = (const float*)d_in[8];
  const float* n2b = (const float*)d_in[9];
  const float* W1  = (const float*)d_in[10];
  const float* b1  = (const float*)d_in[11];
  const float* W2  = (const float*)d_in[12];
  const float* b2  = (const float*)d_in[13];
  unsigned short* wp = (unsigned short*)d_ws;
  float* out = (float*)d_out;

  // pack all weights to bf16 fragment order (one launch; 3168 tiles * 64 lanes)
  pack_all<<<(3168 * 64) / 256, 256, 0, stream>>>(Wu, Wg, A, W1, W2, wp);

  cssm_main<<<NPIX / BMROWS, NTHR, 0, stream>>>(
      x, n1s, n1b, bu, bg, n2s, n2b, b1, b2, wp, out);
}

// Round 10
// 130.937 us; speedup vs baseline: 1.3193x; 1.0032x over previous
//
#include <hip/hip_runtime.h>
#include <hip/hip_bf16.h>

// CSSM TinyViT block, fused bf16-MFMA implementation for gfx950.
// B=16,H=32,W=32 -> 16384 rows of C=384. T=8, HID=1536.
// Round 10 = round 9 base + 16 waves/CU (1024 thr, 4 waves/SIMD):
// waves split 64 pixels into 2 groups of 32 (tile 32pix x 48chan, acc[2][3]).
// y=x+h8 -> out as f32 scratch (same-thread reread, round-6-validated)
// frees bC to double-buffer MLP m-tiles -> 1 barrier/chunk. 15 barriers tot.

#define CCH   384          // global row stride (elements)
#define SB    392          // LDS row stride (ushorts): 384 + 8 pad
#define NPIX  16384
#define BMROWS 64
#define NTHR  1024         // 16 waves: 2 pixel-groups x 8 chan-slots
#define LNEPS 1e-6f
#define HBUF  (BMROWS * SB)   // 25088 ushorts = 49KB per buffer

typedef __attribute__((ext_vector_type(8))) short bf8_t;   // 8 x bf16
typedef __attribute__((ext_vector_type(4))) float f4_t;    // 4 x f32
typedef __attribute__((ext_vector_type(8))) unsigned short us8_t;

// workspace offsets (ushort units). Each 16x16x32 W-tile = 512 bf16 = 1KB.
// K-MAJOR tile order: tile = kb * (N/16) + n16   (kb = K/32 block)
#define OFF_WU 0u
#define OFF_WG 147456u      // 288 tiles * 512
#define OFF_A  294912u
#define OFF_W1 442368u      // 384x1536 -> 1152 tiles
#define OFF_W2 1032192u     // 1536x384 -> 1152 tiles

__device__ __forceinline__ unsigned short f2bf(float f) {
  return __builtin_bit_cast(unsigned short, __float2bfloat16(f));  // HW RNE cvt
}
__device__ __forceinline__ unsigned pack2(float lo, float hi) {
  return (unsigned)f2bf(lo) | ((unsigned)f2bf(hi) << 16);
}
__device__ __forceinline__ float ulo(unsigned u) {
  union { unsigned x; float f; } v; v.x = u << 16; return v.f;
}
__device__ __forceinline__ float uhi(unsigned u) {
  union { unsigned x; float f; } v; v.x = u & 0xffff0000u; return v.f;
}
// sigmoid(z) = 1/(1+2^(-z*log2e))
__device__ __forceinline__ float fsigmoid(float z) {
  return __builtin_amdgcn_rcpf(1.f + exp2f(z * -1.44269504088896f));
}

// Pack all five f32 weights into bf16 fragment order, k-major tiles:
// P[off + tile*512 + lane*8 + j] = W[kb*32 + (lane>>4)*8 + j][n16*16 + (lane&15)]
// Used as the MFMA A-operand: A[row=n][k] = W[k][n] (i.e. W^T).
__global__ void pack_all(const float* __restrict__ Wu, const float* __restrict__ Wg,
                         const float* __restrict__ A,  const float* __restrict__ W1,
                         const float* __restrict__ W2, unsigned short* __restrict__ P) {
  const int gid = blockIdx.x * blockDim.x + threadIdx.x;
  const int l = gid & 63;
  int tile = gid >> 6;
  const float* W; int N; unsigned off; int t;
  if      (tile <  288) { W = Wu; N = 384;  off = OFF_WU; t = tile;        }
  else if (tile <  576) { W = Wg; N = 384;  off = OFF_WG; t = tile - 288;  }
  else if (tile <  864) { W = A;  N = 384;  off = OFF_A;  t = tile - 576;  }
  else if (tile < 2016) { W = W1; N = 1536; off = OFF_W1; t = tile - 864;  }
  else if (tile < 3168) { W = W2; N = 384;  off = OFF_W2; t = tile - 2016; }
  else return;
  const int ntn = N >> 4;
  const int kb  = t / ntn, n16 = t % ntn;
  const int krow = kb * 32 + ((l >> 4) << 3);
  const int col  = n16 * 16 + (l & 15);
  us8_t pk;
  #pragma unroll
  for (int j = 0; j < 8; ++j) pk[j] = f2bf(W[(size_t)(krow + j) * N + col]);
  *reinterpret_cast<us8_t*>(P + off + ((size_t)t << 9) + (l << 3)) = pk;
}

// acc[2][3] += W^T(3 chan-tiles, packed k-major) * X^T(LDS, 2 pixel-tiles
// at pixel base pb). acc[pt][ct]: D[chan][pix] 16x16 tiles; lane holds 4
// consecutive chans of pixel pb + pt*16 + (lane&15).
template <int NKB>
__device__ __forceinline__ void gemm_acc(const unsigned short* sb,
                                         const unsigned short* __restrict__ wt,
                                         int kb0, int ntn, int n16base, int pb,
                                         int lane, f4_t acc[2][3]) {
  const int r    = lane & 15;
  const int koff = (lane >> 4) << 3;
  #pragma unroll 4
  for (int kb = 0; kb < NKB; ++kb) {
    const int ac = kb * 32 + koff;
    bf8_t p[2];                       // B-operand: pixel tiles from LDS
    p[0] = *reinterpret_cast<const bf8_t*>(&sb[(pb + r) * SB + ac]);
    p[1] = *reinterpret_cast<const bf8_t*>(&sb[(pb + 16 + r) * SB + ac]);
    const unsigned short* bt =
        wt + (((size_t)((kb0 + kb) * ntn + n16base) << 9) + (lane << 3));
    #pragma unroll
    for (int ct = 0; ct < 3; ++ct) {
      const bf8_t w = *reinterpret_cast<const bf8_t*>(bt + (ct << 9));
      acc[0][ct] = __builtin_amdgcn_mfma_f32_16x16x32_bf16(w, p[0], acc[0][ct], 0, 0, 0);
      acc[1][ct] = __builtin_amdgcn_mfma_f32_16x16x32_bf16(w, p[1], acc[1][ct], 0, 0, 0);
    }
  }
}

// write transposed C/D tile into padded bf16 LDS [pix][chan] buffer:
// each (pt,ct) quad = 4 consecutive chans of one pixel -> one ds_write_b64.
__device__ __forceinline__ void write_tile(unsigned short* sb, const f4_t t[2][3],
                                           int pb, int ch0, int lane) {
  const int pixb = lane & 15;
  #pragma unroll
  for (int pt = 0; pt < 2; ++pt) {
    const int pix = pb + pt * 16 + pixb;
    #pragma unroll
    for (int ct = 0; ct < 3; ++ct) {
      uint2 v;
      v.x = pack2(t[pt][ct][0], t[pt][ct][1]);
      v.y = pack2(t[pt][ct][2], t[pt][ct][3]);
      *reinterpret_cast<uint2*>(&sb[pix * SB + ch0 + ct * 16]) = v;
    }
  }
}

__device__ __forceinline__ void zero_acc(f4_t a[2][3]) {
  #pragma unroll
  for (int pt = 0; pt < 2; ++pt)
    #pragma unroll
    for (int ct = 0; ct < 3; ++ct) a[pt][ct] = (f4_t){0.f, 0.f, 0.f, 0.f};
}

__global__ __launch_bounds__(NTHR, 1) void cssm_main(
    const float* __restrict__ x,
    const float* __restrict__ n1s, const float* __restrict__ n1b,
    const float* __restrict__ bu, const float* __restrict__ bg,
    const float* __restrict__ n2s, const float* __restrict__ n2b,
    const float* __restrict__ b1, const float* __restrict__ b2,
    const unsigned short* __restrict__ wp,
    float* __restrict__ out) {
  __shared__ unsigned short sm[3 * HBUF];   // bA | bB | bC
  __shared__ float part[64][8][2];          // per-(pixel,chan-slot) LN2 partials
  __shared__ float srow[64][2];             // LN2 mu, rs per pixel
  unsigned short* bA = sm;                  // xn -> h ping -> xn2
  unsigned short* bB = sm + HBUF;           // h pong -> m even chunks
  unsigned short* bC = sm + 2 * HBUF;       // m odd chunks

  const int tid = threadIdx.x;
  const int lane = tid & 63;
  const int wv = tid >> 6;                  // 0..15
  const int nw = wv & 7;                    // chan-slot: chans nw*48..+47
  const int pb = (wv >> 3) << 5;            // pixel base: 0 or 32
  const int r0 = blockIdx.x * BMROWS;
  const int pixb = lane & 15;
  const int ch0  = nw * 48 + ((lane >> 4) << 2);

  // ---------------- Phase A: LN1(x) -> bA (bf16 [pix][chan], padded) -------
  {
    const int row = tid >> 4, seg = tid & 15;    // 16 thr/row, 24 elems each
    const float* xr = x + (size_t)(r0 + row) * CCH + seg * 24;
    float v[24];
    float s = 0.f, s2 = 0.f;
    #pragma unroll
    for (int i = 0; i < 6; ++i) {
      const f4_t t = reinterpret_cast<const f4_t*>(xr)[i];
      #pragma unroll
      for (int j = 0; j < 4; ++j) { const float f = t[j]; v[i * 4 + j] = f; s += f; s2 += f * f; }
    }
    #pragma unroll
    for (int o = 1; o < 16; o <<= 1) { s += __shfl_xor(s, o, 64); s2 += __shfl_xor(s2, o, 64); }
    const float mu = s * (1.f / CCH);
    const float rs = rsqrtf(fmaxf(s2 * (1.f / CCH) - mu * mu, 0.f) + LNEPS);
    #pragma unroll
    for (int g8 = 0; g8 < 3; ++g8) {
      us8_t pk;
      #pragma unroll
      for (int j = 0; j < 8; ++j) {
        const int colc = seg * 24 + g8 * 8 + j;
        pk[j] = f2bf((v[g8 * 8 + j] - mu) * rs * n1s[colc] + n1b[colc]);
      }
      *reinterpret_cast<us8_t*>(&bA[row * SB + seg * 24 + g8 * 8]) = pk;
    }
  }
  __syncthreads();

  // ---------------- Phase A2: g, c -> packed regs; h1 -> bB ----------------
  f4_t acc[2][3];
  unsigned gp[2][3][2], cp[2][3][2];
  zero_acc(acc);
  gemm_acc<12>(bA, wp + OFF_WG, 0, 24, nw * 3, pb, lane, acc);
  #pragma unroll
  for (int ct = 0; ct < 3; ++ct) {
    const f4_t bgq = *reinterpret_cast<const f4_t*>(&bg[ch0 + ct * 16]);
    #pragma unroll
    for (int pt = 0; pt < 2; ++pt) {
      gp[pt][ct][0] = pack2(fsigmoid(acc[pt][ct][0] + bgq[0]),
                            fsigmoid(acc[pt][ct][1] + bgq[1]));
      gp[pt][ct][1] = pack2(fsigmoid(acc[pt][ct][2] + bgq[2]),
                            fsigmoid(acc[pt][ct][3] + bgq[3]));
    }
  }
  zero_acc(acc);
  gemm_acc<12>(bA, wp + OFF_WU, 0, 24, nw * 3, pb, lane, acc);
  #pragma unroll
  for (int ct = 0; ct < 3; ++ct) {
    const f4_t buq = *reinterpret_cast<const f4_t*>(&bu[ch0 + ct * 16]);
    #pragma unroll
    for (int pt = 0; pt < 2; ++pt) {
      #pragma unroll
      for (int p = 0; p < 2; ++p) {
        const unsigned g = gp[pt][ct][p];
        const float c0 = (1.f - ulo(g)) * (acc[pt][ct][2 * p]     + buq[2 * p]);
        const float c1 = (1.f - uhi(g)) * (acc[pt][ct][2 * p + 1] + buq[2 * p + 1]);
        acc[pt][ct][2 * p] = c0; acc[pt][ct][2 * p + 1] = c1;
        cp[pt][ct][p] = pack2(c0, c1);
      }
    }
  }
  write_tile(bB, acc, pb, ch0, lane);       // h1 = c (bA reads done above)
  __syncthreads();

  // ---------------- Phase B: h' = g*(h@A) + c, ping-pong bB/bA -------------
  {
    unsigned short* cur = bB;
    unsigned short* alt = bA;
    #pragma unroll 1
    for (int stp = 0; stp < 7; ++stp) {     // h2..h8
      zero_acc(acc);
      gemm_acc<12>(cur, wp + OFF_A, 0, 24, nw * 3, pb, lane, acc);
      #pragma unroll
      for (int pt = 0; pt < 2; ++pt)
        #pragma unroll
        for (int ct = 0; ct < 3; ++ct)
          #pragma unroll
          for (int p = 0; p < 2; ++p) {
            const unsigned g = gp[pt][ct][p], c = cp[pt][ct][p];
            acc[pt][ct][2 * p]     = ulo(g) * acc[pt][ct][2 * p]     + ulo(c);
            acc[pt][ct][2 * p + 1] = uhi(g) * acc[pt][ct][2 * p + 1] + uhi(c);
          }
      if (stp < 6) {
        write_tile(alt, acc, pb, ch0, lane);  // write buffer nobody is reading
        unsigned short* t = cur; cur = alt; alt = t;
        __syncthreads();
      }
    }
  }
  // last recurrence reads hit bB (fenced later); bA reads fenced at stp5.

  // ------- Phase C: y = x + h8 -> out (f32 scratch); LN2 -> xn2 in bA ------
  #pragma unroll
  for (int pt = 0; pt < 2; ++pt) {
    const int pix = pb + pt * 16 + pixb;
    float s = 0.f, s2 = 0.f;
    #pragma unroll
    for (int ct = 0; ct < 3; ++ct) {
      const size_t pos = (size_t)(r0 + pix) * CCH + ch0 + ct * 16;
      const f4_t xq = *reinterpret_cast<const f4_t*>(&x[pos]);
      f4_t yq;
      #pragma unroll
      for (int j = 0; j < 4; ++j) {
        const float y = xq[j] + acc[pt][ct][j];
        yq[j] = y; acc[pt][ct][j] = y;
        s += y; s2 += y * y;
      }
      *reinterpret_cast<f4_t*>(&out[pos]) = yq;   // same-thread reread in E
    }
    s += __shfl_xor(s, 16, 64); s2 += __shfl_xor(s2, 16, 64);
    s += __shfl_xor(s, 32, 64); s2 += __shfl_xor(s2, 32, 64);
    if (lane < 16) { part[pix][nw][0] = s; part[pix][nw][1] = s2; }
  }
  __syncthreads();
  if (tid < 64) {
    float s = 0.f, s2 = 0.f;
    #pragma unroll
    for (int w = 0; w < 8; ++w) { s += part[tid][w][0]; s2 += part[tid][w][1]; }
    const float mu = s * (1.f / CCH);
    srow[tid][0] = mu;
    srow[tid][1] = rsqrtf(fmaxf(s2 * (1.f / CCH) - mu * mu, 0.f) + LNEPS);
  }
  __syncthreads();
  {
    f4_t scq[3], bsq[3];
    #pragma unroll
    for (int ct = 0; ct < 3; ++ct) {
      scq[ct] = *reinterpret_cast<const f4_t*>(&n2s[ch0 + ct * 16]);
      bsq[ct] = *reinterpret_cast<const f4_t*>(&n2b[ch0 + ct * 16]);
    }
    #pragma unroll
    for (int pt = 0; pt < 2; ++pt) {
      const int pix = pb + pt * 16 + pixb;
      const float mu = srow[pix][0], rs = srow[pix][1];
      #pragma unroll
      for (int ct = 0; ct < 3; ++ct)
        #pragma unroll
        for (int j = 0; j < 4; ++j)
          acc[pt][ct][j] = (acc[pt][ct][j] - mu) * rs * scq[ct][j] + bsq[ct][j];
    }
    write_tile(bA, acc, pb, ch0, lane);     // xn2 (bA reads fenced at stp5)
  }
  __syncthreads();

  // ------- Phase D: MLP in 4 HID-chunks, m double-buffered bB/bC -----------
  f4_t aco[2][3];
  zero_acc(aco);                            // MFMA-only until E -> AGPR
  #pragma unroll 1
  for (int ch = 0; ch < 4; ++ch) {
    unsigned short* buf = (ch & 1) ? bC : bB;
    zero_acc(acc);
    gemm_acc<12>(bA, wp + OFF_W1, 0, 96, ch * 24 + nw * 3, pb, lane, acc);
    #pragma unroll
    for (int ct = 0; ct < 3; ++ct) {
      const f4_t b1q = *reinterpret_cast<const f4_t*>(&b1[ch * 384 + ch0 + ct * 16]);
      #pragma unroll
      for (int pt = 0; pt < 2; ++pt)
        #pragma unroll
        for (int j = 0; j < 4; ++j) {
          // gelu(z) = z / (1 + 2^(-2.3021178*(z + 0.044715 z^3)))
          const float z = acc[pt][ct][j] + b1q[j];
          const float m = z * z;
          const float t = z * fmaf(m, 0.044715f, 1.0f);
          const float e = exp2f(t * -2.30211774f);
          acc[pt][ct][j] = z * __builtin_amdgcn_rcpf(1.f + e);
        }
    }
    write_tile(buf, acc, pb, ch0, lane);
    __syncthreads();                        // buf complete; prev buf readers
                                            // passed the previous barrier
    gemm_acc<12>(buf, wp + OFF_W2, ch * 12, 24, nw * 3, pb, lane, aco);
  }

  // ---------------- Phase E: out = y + mlp + b2 (same-thread reread) -------
  {
    f4_t b2q[3];
    #pragma unroll
    for (int ct = 0; ct < 3; ++ct)
      b2q[ct] = *reinterpret_cast<const f4_t*>(&b2[ch0 + ct * 16]);
    #pragma unroll
    for (int pt = 0; pt < 2; ++pt) {
      const int pix = pb + pt * 16 + pixb;
      #pragma unroll
      for (int ct = 0; ct < 3; ++ct) {
        const size_t pos = (size_t)(r0 + pix) * CCH + ch0 + ct * 16;
        const f4_t yq = *reinterpret_cast<const f4_t*>(&out[pos]);
        f4_t o;
        #pragma unroll
        for (int j = 0; j < 4; ++j)
          o[j] = yq[j] + aco[pt][ct][j] + b2q[ct][j];
        *reinterpret_cast<f4_t*>(&out[pos]) = o;
      }
    }
  }
}

extern "C" void kernel_launch(void* const* d_in, const int* in_sizes, int n_in,
                              void* d_out, int out_size, void* d_ws, size_t ws_size,
                              hipStream_t stream) {
  const float* x   = (const float*)d_in[0];
  const float* n1s = (const float*)d_in[1];
  const float* n1b = (const float*)d_in[2];
  const float* Wu  = (const float*)d_in[3];
  const float* bu  = (const float*)d_in[4];
  const float* Wg  = (const float*)d_in[5];
  const float* bg  = (const float*)d_in[6];
  const float* A   = (const float*)d_in[7];
  const float* n2s = (const float*)d_in[8];
  const float* n2b = (const float*)d_in[9];
  const float* W1  = (const float*)d_in[10];
  const float* b1  = (const float*)d_in[11];
  const float* W2  = (const float*)d_in[12];
  const float* b2  = (const float*)d_in[13];
  unsigned short* wp = (unsigned short*)d_ws;
  float* out = (float*)d_out;

  // pack all weights to bf16 fragment order (one launch; 3168 tiles * 64 lanes)
  pack_all<<<(3168 * 64) / 256, 256, 0, stream>>>(Wu, Wg, A, W1, W2, wp);

  cssm_main<<<NPIX / BMROWS, NTHR, 0, stream>>>(
      x, n1s, n1b, bu, bg, n2s, n2b, b1, b2, wp, out);
}